// Round 3
// baseline (48.054 us; speedup 1.0000x reference)
//
#include <hip/hip_runtime.h>

// Head: fused GEMM (M=204800, K=128, N=84->96 padded) + DFL softmax + box decode + sigmoid.
// R3: two-kernel scheme. prep_kernel transposes/converts weights into d_ws once
// (f16 Wt[96][128] + f32 bias[96]); head_kernel has NO LDS and NO barrier --
// weight fragments read directly from global (L2/L3-resident), x loads issue at
// wave start. All divisions via v_rcp_f32.

typedef _Float16 half8 __attribute__((ext_vector_type(8)));
typedef float f32x4v __attribute__((ext_vector_type(4)));

constexpr int Ww = 80;
constexpr int HW = 6400;
constexpr int Cc = 128;
constexpr int NPAD = 96;             // 6 N-tiles of 16: 64 box + 20 cls + 12 pad

__global__ void prep_kernel(const float* __restrict__ w_box,
                            const float* __restrict__ b_box,
                            const float* __restrict__ w_cls,
                            const float* __restrict__ b_cls,
                            _Float16* __restrict__ wt,    // [96][128], ch-major
                            float* __restrict__ bias)     // [96]
{
    int idx = blockIdx.x * 256 + threadIdx.x;             // 48 blocks x 256
    if (idx < NPAD * Cc) {
        int ch = idx >> 7;
        int k  = idx & 127;
        float v = 0.f;
        if (ch < 64)      v = w_box[k * 64 + ch];
        else if (ch < 84) v = w_cls[k * 20 + (ch - 64)];
        wt[idx] = (_Float16)v;
    }
    if (idx < NPAD) {
        float bv = 0.f;
        if (idx < 64)      bv = b_box[idx];
        else if (idx < 84) bv = b_cls[idx - 64];
        bias[idx] = bv;
    }
}

__device__ __forceinline__ float sigm(float v) {
    return __builtin_amdgcn_rcpf(1.f + __expf(-v));
}

__global__ void head_kernel(const float* __restrict__ x,
                            const _Float16* __restrict__ wt,
                            const float* __restrict__ bias,
                            const int* __restrict__ stride_p,
                            float* __restrict__ out)
{
    const int tid  = threadIdx.x;
    const int wave = tid >> 6;
    const int lane = tid & 63;
    const int c    = lane & 15;     // A channel-in-tile / B spatial-row / D col
    const int g    = lane >> 4;     // quarter-group; D row = 4g + reg

    const int mbase = blockIdx.x * 128 + wave * 32;      // 1600 blocks

    // ---- x loads first: 16 dwordx4 to HBM, issue ASAP ----
    f32x4v xv[4][2][2];
    const float* xbase = x + (size_t)(mbase + c) * Cc + g * 8;
    #pragma unroll
    for (int ks = 0; ks < 4; ++ks)
        #pragma unroll
        for (int rt = 0; rt < 2; ++rt) {
            const float* p = xbase + rt * 16 * Cc + ks * 32;
            xv[ks][rt][0] = *(const f32x4v*)p;
            xv[ks][rt][1] = *(const f32x4v*)(p + 4);
        }

    f32x4v acc[2][6];
    #pragma unroll
    for (int i = 0; i < 2; ++i)
        #pragma unroll
        for (int j = 0; j < 6; ++j)
            acc[i][j] = (f32x4v){0.f, 0.f, 0.f, 0.f};

    #pragma unroll
    for (int ks = 0; ks < 4; ++ks) {
        half8 wfrag[6];
        #pragma unroll
        for (int nt = 0; nt < 6; ++nt)
            wfrag[nt] = *(const half8*)&wt[(nt * 16 + c) * Cc + ks * 32 + g * 8];

        #pragma unroll
        for (int rt = 0; rt < 2; ++rt) {
            f32x4v lo = xv[ks][rt][0], hi = xv[ks][rt][1];
            half8 b;
            b[0] = (_Float16)lo[0]; b[1] = (_Float16)lo[1];
            b[2] = (_Float16)lo[2]; b[3] = (_Float16)lo[3];
            b[4] = (_Float16)hi[0]; b[5] = (_Float16)hi[1];
            b[6] = (_Float16)hi[2]; b[7] = (_Float16)hi[3];
            #pragma unroll
            for (int nt = 0; nt < 6; ++nt)
                acc[rt][nt] = __builtin_amdgcn_mfma_f32_16x16x32_f16(wfrag[nt], b, acc[rt][nt], 0, 0, 0);
        }
    }

    const float sf = (float)stride_p[0];
    f32x4v bl[6];
    #pragma unroll
    for (int nt = 0; nt < 6; ++nt)
        bl[nt] = *(const f32x4v*)&bias[nt * 16 + g * 4];

    #pragma unroll
    for (int rt = 0; rt < 2; ++rt) {
        const int m   = mbase + rt * 16 + c;
        const int pos = m % HW;
        const int yp  = pos / Ww;
        const int xq  = pos - yp * Ww;
        const float ax = ((float)xq + 0.5f) * sf;
        const float ay = ((float)yp + 0.5f) * sf;

        // DFL softmax: channels t*16 + 4g + r; lane-local over r, 2 shfls over g.
        float dfl[4];
        #pragma unroll
        for (int t = 0; t < 4; ++t) {
            f32x4v v = acc[rt][t] + bl[t];
            float e0 = __expf(v[0]), e1 = __expf(v[1]);
            float e2 = __expf(v[2]), e3 = __expf(v[3]);
            float s  = e0 + e1 + e2 + e3;
            float ws = e1 + 2.f * e2 + 3.f * e3 + (float)(4 * g) * s;
            s  += __shfl_xor(s, 16, 64);
            s  += __shfl_xor(s, 32, 64);
            ws += __shfl_xor(ws, 16, 64);
            ws += __shfl_xor(ws, 32, 64);
            dfl[t] = ws * __builtin_amdgcn_rcpf(s);
        }
        const float w2 = dfl[2] - dfl[0], w3 = dfl[3] - dfl[1];

        float* op = out + (size_t)m * 24;

        // cls 0..15: ch 64+4g+r -> out[4+4g+r]
        f32x4v vA = acc[rt][4] + bl[4];
        f32x4v clsA;
        clsA[0] = sigm(vA[0]); clsA[1] = sigm(vA[1]);
        clsA[2] = sigm(vA[2]); clsA[3] = sigm(vA[3]);
        *(f32x4v*)(op + 4 + 4 * g) = clsA;

        if (g == 0) {
            f32x4v box = { ax + 0.5f * w2, ay + 0.5f * w3, w2, w3 };
            *(f32x4v*)op = box;
            f32x4v vB = acc[rt][5] + bl[5];
            f32x4v clsB;
            clsB[0] = sigm(vB[0]); clsB[1] = sigm(vB[1]);
            clsB[2] = sigm(vB[2]); clsB[3] = sigm(vB[3]);
            *(f32x4v*)(op + 20) = clsB;
        }
    }
}

extern "C" void kernel_launch(void* const* d_in, const int* in_sizes, int n_in,
                              void* d_out, int out_size, void* d_ws, size_t ws_size,
                              hipStream_t stream) {
    const float* x      = (const float*)d_in[0];
    const float* w_box  = (const float*)d_in[1];
    const float* b_box  = (const float*)d_in[2];
    const float* w_cls  = (const float*)d_in[3];
    const float* b_cls  = (const float*)d_in[4];
    const int*   stride_p = (const int*)d_in[5];
    float* out = (float*)d_out;

    _Float16* wt  = (_Float16*)d_ws;                       // 96*128*2 = 24576 B
    float*    bia = (float*)((char*)d_ws + NPAD * Cc * 2); // 384 B

    hipLaunchKernelGGL(prep_kernel, dim3(48), dim3(256), 0, stream,
                       w_box, b_box, w_cls, b_cls, wt, bia);
    hipLaunchKernelGGL(head_kernel, dim3(1600), dim3(256), 0, stream,
                       x, wt, bia, stride_p, out);
}

// Round 4
// 35.831 us; speedup vs baseline: 1.3411x; 1.3411x over previous
//
#include <hip/hip_runtime.h>

// Head: fused GEMM (M=204800, K=128, N=84->96 padded) + DFL softmax + box decode + sigmoid.
// R4 = R2 (single kernel, LDS-staged f16 weights, swapped-operand MFMA) with:
//   (a) x preloaded BEFORE weight staging so HBM latency hides under prologue+barrier,
//   (b) v_rcp_f32 instead of full-precision divides in the epilogue.

typedef _Float16 half8 __attribute__((ext_vector_type(8)));
typedef float f32x4v __attribute__((ext_vector_type(4)));

constexpr int Ww = 80;
constexpr int HW = 6400;
constexpr int Cc = 128;
constexpr int NPAD = 96;             // 6 N-tiles of 16: 64 box + 20 cls + 12 pad
constexpr int WT_STRIDE = 136;       // f16 elems; 272B row -> 2-way bank alias (free)

__device__ __forceinline__ float sigm(float v) {
    return __builtin_amdgcn_rcpf(1.f + __expf(-v));
}

__global__ void head_kernel(const float* __restrict__ x,
                            const float* __restrict__ w_box,
                            const float* __restrict__ b_box,
                            const float* __restrict__ w_cls,
                            const float* __restrict__ b_cls,
                            const int*   __restrict__ stride_p,
                            float* __restrict__ out)
{
    __shared__ __align__(16) _Float16 Wt[NPAD][WT_STRIDE]; // Wt[ch][k]
    __shared__ __align__(16) float bias_s[NPAD];

    const int tid  = threadIdx.x;
    const int wave = tid >> 6;
    const int lane = tid & 63;
    const int c    = lane & 15;     // A channel-in-tile / B spatial-row / D col
    const int g    = lane >> 4;     // quarter-group; D row = 4g + reg

    const int mbase = blockIdx.x * 128 + wave * 32;      // 1600 blocks

    // ---- (a) x loads FIRST: 16 dwordx4 issue before any staging work ----
    f32x4v xv[4][2][2];
    const float* xbase = x + (size_t)(mbase + c) * Cc + g * 8;
    #pragma unroll
    for (int ks = 0; ks < 4; ++ks)
        #pragma unroll
        for (int rt = 0; rt < 2; ++rt) {
            const float* p = xbase + rt * 16 * Cc + ks * 32;
            xv[ks][rt][0] = *(const f32x4v*)p;
            xv[ks][rt][1] = *(const f32x4v*)(p + 4);
        }

    // ---- stage Wt[ch][k] = w[k][ch] (f16), vectorized float4 along ch ----
    for (int i = tid; i < 128 * 16; i += 256) {          // box: 8 iters/thread
        int k  = i >> 4;
        int c4 = (i & 15) << 2;
        f32x4v v = *(const f32x4v*)&w_box[k * 64 + c4];
        Wt[c4 + 0][k] = (_Float16)v[0];
        Wt[c4 + 1][k] = (_Float16)v[1];
        Wt[c4 + 2][k] = (_Float16)v[2];
        Wt[c4 + 3][k] = (_Float16)v[3];
    }
    for (int i = tid; i < 128 * 5; i += 256) {           // cls: ~2.5 iters/thread
        int k  = i / 5;
        int c4 = (i - k * 5) << 2;
        f32x4v v = *(const f32x4v*)&w_cls[k * 20 + c4];
        Wt[64 + c4 + 0][k] = (_Float16)v[0];
        Wt[64 + c4 + 1][k] = (_Float16)v[1];
        Wt[64 + c4 + 2][k] = (_Float16)v[2];
        Wt[64 + c4 + 3][k] = (_Float16)v[3];
    }
    for (int i = tid; i < 12 * 128; i += 256) {          // zero pad ch 84..95
        int ch = 84 + (i >> 7);
        int k  = i & 127;
        Wt[ch][k] = (_Float16)0.f;
    }
    if (tid < NPAD) {
        float bv = 0.f;
        if (tid < 64)      bv = b_box[tid];
        else if (tid < 84) bv = b_cls[tid - 64];
        bias_s[tid] = bv;
    }
    __syncthreads();

    f32x4v acc[2][6];
    #pragma unroll
    for (int i = 0; i < 2; ++i)
        #pragma unroll
        for (int j = 0; j < 6; ++j)
            acc[i][j] = (f32x4v){0.f, 0.f, 0.f, 0.f};

    #pragma unroll
    for (int ks = 0; ks < 4; ++ks) {
        half8 wfrag[6];
        #pragma unroll
        for (int nt = 0; nt < 6; ++nt)
            wfrag[nt] = *(const half8*)&Wt[nt * 16 + c][ks * 32 + g * 8];

        #pragma unroll
        for (int rt = 0; rt < 2; ++rt) {
            f32x4v lo = xv[ks][rt][0], hi = xv[ks][rt][1];
            half8 b;
            b[0] = (_Float16)lo[0]; b[1] = (_Float16)lo[1];
            b[2] = (_Float16)lo[2]; b[3] = (_Float16)lo[3];
            b[4] = (_Float16)hi[0]; b[5] = (_Float16)hi[1];
            b[6] = (_Float16)hi[2]; b[7] = (_Float16)hi[3];
            #pragma unroll
            for (int nt = 0; nt < 6; ++nt)
                acc[rt][nt] = __builtin_amdgcn_mfma_f32_16x16x32_f16(wfrag[nt], b, acc[rt][nt], 0, 0, 0);
        }
    }

    const float sf = (float)stride_p[0];
    f32x4v bl[6];
    #pragma unroll
    for (int nt = 0; nt < 6; ++nt)
        bl[nt] = *(const f32x4v*)&bias_s[nt * 16 + g * 4];

    #pragma unroll
    for (int rt = 0; rt < 2; ++rt) {
        const int m   = mbase + rt * 16 + c;
        const int pos = m % HW;
        const int yp  = pos / Ww;
        const int xq  = pos - yp * Ww;
        const float ax = ((float)xq + 0.5f) * sf;
        const float ay = ((float)yp + 0.5f) * sf;

        // DFL softmax: channels t*16 + 4g + r; lane-local over r, 2 shfls over g.
        float dfl[4];
        #pragma unroll
        for (int t = 0; t < 4; ++t) {
            f32x4v v = acc[rt][t] + bl[t];
            float e0 = __expf(v[0]), e1 = __expf(v[1]);
            float e2 = __expf(v[2]), e3 = __expf(v[3]);
            float s  = e0 + e1 + e2 + e3;
            float ws = e1 + 2.f * e2 + 3.f * e3 + (float)(4 * g) * s;
            s  += __shfl_xor(s, 16, 64);
            s  += __shfl_xor(s, 32, 64);
            ws += __shfl_xor(ws, 16, 64);
            ws += __shfl_xor(ws, 32, 64);
            dfl[t] = ws * __builtin_amdgcn_rcpf(s);
        }
        const float w2 = dfl[2] - dfl[0], w3 = dfl[3] - dfl[1];

        float* op = out + (size_t)m * 24;

        // cls 0..15: ch 64+4g+r -> out[4+4g+r]
        f32x4v vA = acc[rt][4] + bl[4];
        f32x4v clsA;
        clsA[0] = sigm(vA[0]); clsA[1] = sigm(vA[1]);
        clsA[2] = sigm(vA[2]); clsA[3] = sigm(vA[3]);
        *(f32x4v*)(op + 4 + 4 * g) = clsA;

        if (g == 0) {
            f32x4v box = { ax + 0.5f * w2, ay + 0.5f * w3, w2, w3 };
            *(f32x4v*)op = box;
            f32x4v vB = acc[rt][5] + bl[5];
            f32x4v clsB;
            clsB[0] = sigm(vB[0]); clsB[1] = sigm(vB[1]);
            clsB[2] = sigm(vB[2]); clsB[3] = sigm(vB[3]);
            *(f32x4v*)(op + 20) = clsB;
        }
    }
}

extern "C" void kernel_launch(void* const* d_in, const int* in_sizes, int n_in,
                              void* d_out, int out_size, void* d_ws, size_t ws_size,
                              hipStream_t stream) {
    const float* x      = (const float*)d_in[0];
    const float* w_box  = (const float*)d_in[1];
    const float* b_box  = (const float*)d_in[2];
    const float* w_cls  = (const float*)d_in[3];
    const float* b_cls  = (const float*)d_in[4];
    const int*   stride_p = (const int*)d_in[5];
    float* out = (float*)d_out;

    dim3 grid(1600), block(256);
    hipLaunchKernelGGL(head_kernel, grid, block, 0, stream,
                       x, w_box, b_box, w_cls, b_cls, stride_p, out);
}

// Round 5
// 35.359 us; speedup vs baseline: 1.3590x; 1.0134x over previous
//
#include <hip/hip_runtime.h>

// Head: fused GEMM (M=204800, K=128, N=84->96 padded) + DFL softmax + box decode + sigmoid.
// R5 = R4 + __launch_bounds__(256,3) (VGPR cap ~168 so all 16 x-loads stay in flight)
//        + sched_barrier(0) pinning the x-load issue before weight staging.

typedef _Float16 half8 __attribute__((ext_vector_type(8)));
typedef float f32x4v __attribute__((ext_vector_type(4)));

constexpr int Ww = 80;
constexpr int HW = 6400;
constexpr int Cc = 128;
constexpr int NPAD = 96;             // 6 N-tiles of 16: 64 box + 20 cls + 12 pad
constexpr int WT_STRIDE = 136;       // f16 elems; 272B row -> 2-way bank alias (free)

__device__ __forceinline__ float sigm(float v) {
    return __builtin_amdgcn_rcpf(1.f + __expf(-v));
}

__global__ __launch_bounds__(256, 3)
void head_kernel(const float* __restrict__ x,
                 const float* __restrict__ w_box,
                 const float* __restrict__ b_box,
                 const float* __restrict__ w_cls,
                 const float* __restrict__ b_cls,
                 const int*   __restrict__ stride_p,
                 float* __restrict__ out)
{
    __shared__ __align__(16) _Float16 Wt[NPAD][WT_STRIDE]; // Wt[ch][k]
    __shared__ __align__(16) float bias_s[NPAD];

    const int tid  = threadIdx.x;
    const int wave = tid >> 6;
    const int lane = tid & 63;
    const int c    = lane & 15;     // A channel-in-tile / B spatial-row / D col
    const int g    = lane >> 4;     // quarter-group; D row = 4g + reg

    const int mbase = blockIdx.x * 128 + wave * 32;      // 1600 blocks

    // ---- x loads FIRST: 16 dwordx4 issue before any staging work ----
    f32x4v xv[4][2][2];
    const float* xbase = x + (size_t)(mbase + c) * Cc + g * 8;
    #pragma unroll
    for (int ks = 0; ks < 4; ++ks)
        #pragma unroll
        for (int rt = 0; rt < 2; ++rt) {
            const float* p = xbase + rt * 16 * Cc + ks * 32;
            xv[ks][rt][0] = *(const f32x4v*)p;
            xv[ks][rt][1] = *(const f32x4v*)(p + 4);
        }
    // Pin: nothing moves across -- the 16 loads are issued HERE, before staging.
    __builtin_amdgcn_sched_barrier(0);

    // ---- stage Wt[ch][k] = w[k][ch] (f16), vectorized float4 along ch ----
    for (int i = tid; i < 128 * 16; i += 256) {          // box: 8 iters/thread
        int k  = i >> 4;
        int c4 = (i & 15) << 2;
        f32x4v v = *(const f32x4v*)&w_box[k * 64 + c4];
        Wt[c4 + 0][k] = (_Float16)v[0];
        Wt[c4 + 1][k] = (_Float16)v[1];
        Wt[c4 + 2][k] = (_Float16)v[2];
        Wt[c4 + 3][k] = (_Float16)v[3];
    }
    for (int i = tid; i < 128 * 5; i += 256) {           // cls: ~2.5 iters/thread
        int k  = i / 5;
        int c4 = (i - k * 5) << 2;
        f32x4v v = *(const f32x4v*)&w_cls[k * 20 + c4];
        Wt[64 + c4 + 0][k] = (_Float16)v[0];
        Wt[64 + c4 + 1][k] = (_Float16)v[1];
        Wt[64 + c4 + 2][k] = (_Float16)v[2];
        Wt[64 + c4 + 3][k] = (_Float16)v[3];
    }
    for (int i = tid; i < 12 * 128; i += 256) {          // zero pad ch 84..95
        int ch = 84 + (i >> 7);
        int k  = i & 127;
        Wt[ch][k] = (_Float16)0.f;
    }
    if (tid < NPAD) {
        float bv = 0.f;
        if (tid < 64)      bv = b_box[tid];
        else if (tid < 84) bv = b_cls[tid - 64];
        bias_s[tid] = bv;
    }
    __syncthreads();   // drains vmcnt(0): x has landed by here, in the staging shadow

    f32x4v acc[2][6];
    #pragma unroll
    for (int i = 0; i < 2; ++i)
        #pragma unroll
        for (int j = 0; j < 6; ++j)
            acc[i][j] = (f32x4v){0.f, 0.f, 0.f, 0.f};

    #pragma unroll
    for (int ks = 0; ks < 4; ++ks) {
        half8 wfrag[6];
        #pragma unroll
        for (int nt = 0; nt < 6; ++nt)
            wfrag[nt] = *(const half8*)&Wt[nt * 16 + c][ks * 32 + g * 8];

        #pragma unroll
        for (int rt = 0; rt < 2; ++rt) {
            f32x4v lo = xv[ks][rt][0], hi = xv[ks][rt][1];
            half8 b;
            b[0] = (_Float16)lo[0]; b[1] = (_Float16)lo[1];
            b[2] = (_Float16)lo[2]; b[3] = (_Float16)lo[3];
            b[4] = (_Float16)hi[0]; b[5] = (_Float16)hi[1];
            b[6] = (_Float16)hi[2]; b[7] = (_Float16)hi[3];
            #pragma unroll
            for (int nt = 0; nt < 6; ++nt)
                acc[rt][nt] = __builtin_amdgcn_mfma_f32_16x16x32_f16(wfrag[nt], b, acc[rt][nt], 0, 0, 0);
        }
    }

    const float sf = (float)stride_p[0];
    f32x4v bl[6];
    #pragma unroll
    for (int nt = 0; nt < 6; ++nt)
        bl[nt] = *(const f32x4v*)&bias_s[nt * 16 + g * 4];

    #pragma unroll
    for (int rt = 0; rt < 2; ++rt) {
        const int m   = mbase + rt * 16 + c;
        const int pos = m % HW;
        const int yp  = pos / Ww;
        const int xq  = pos - yp * Ww;
        const float ax = ((float)xq + 0.5f) * sf;
        const float ay = ((float)yp + 0.5f) * sf;

        // DFL softmax: channels t*16 + 4g + r; lane-local over r, 2 shfls over g.
        float dfl[4];
        #pragma unroll
        for (int t = 0; t < 4; ++t) {
            f32x4v v = acc[rt][t] + bl[t];
            float e0 = __expf(v[0]), e1 = __expf(v[1]);
            float e2 = __expf(v[2]), e3 = __expf(v[3]);
            float s  = e0 + e1 + e2 + e3;
            float ws = e1 + 2.f * e2 + 3.f * e3 + (float)(4 * g) * s;
            s  += __shfl_xor(s, 16, 64);
            s  += __shfl_xor(s, 32, 64);
            ws += __shfl_xor(ws, 16, 64);
            ws += __shfl_xor(ws, 32, 64);
            dfl[t] = ws * __builtin_amdgcn_rcpf(s);
        }
        const float w2 = dfl[2] - dfl[0], w3 = dfl[3] - dfl[1];

        float* op = out + (size_t)m * 24;

        // cls 0..15: ch 64+4g+r -> out[4+4g+r]
        f32x4v vA = acc[rt][4] + bl[4];
        f32x4v clsA;
        clsA[0] = sigm(vA[0]); clsA[1] = sigm(vA[1]);
        clsA[2] = sigm(vA[2]); clsA[3] = sigm(vA[3]);
        *(f32x4v*)(op + 4 + 4 * g) = clsA;

        if (g == 0) {
            f32x4v box = { ax + 0.5f * w2, ay + 0.5f * w3, w2, w3 };
            *(f32x4v*)op = box;
            f32x4v vB = acc[rt][5] + bl[5];
            f32x4v clsB;
            clsB[0] = sigm(vB[0]); clsB[1] = sigm(vB[1]);
            clsB[2] = sigm(vB[2]); clsB[3] = sigm(vB[3]);
            *(f32x4v*)(op + 20) = clsB;
        }
    }
}

extern "C" void kernel_launch(void* const* d_in, const int* in_sizes, int n_in,
                              void* d_out, int out_size, void* d_ws, size_t ws_size,
                              hipStream_t stream) {
    const float* x      = (const float*)d_in[0];
    const float* w_box  = (const float*)d_in[1];
    const float* b_box  = (const float*)d_in[2];
    const float* w_cls  = (const float*)d_in[3];
    const float* b_cls  = (const float*)d_in[4];
    const int*   stride_p = (const int*)d_in[5];
    float* out = (float*)d_out;

    dim3 grid(1600), block(256);
    hipLaunchKernelGGL(head_kernel, grid, block, 0, stream,
                       x, w_box, b_box, w_cls, b_cls, stride_p, out);
}